// Round 4
// baseline (1604.428 us; speedup 1.0000x reference)
//
#include <hip/hip_runtime.h>
#include <stdint.h>

#define NL  16
#define NE  16384           // entries per level (power of two)
#define BLK 512             // threads per block
#define PPT 4               // points per thread -> 2048 points per block

constexpr int kRes[NL] = {16,20,25,32,40,50,64,80,101,128,161,203,256,322,406,512};

// ---------------- pre-pass: pack emb (L,2,NE) fp32 -> (L,NE) u32 of 2x bf16 ----------------
__global__ void pack_kernel(const float* __restrict__ emb, uint32_t* __restrict__ tbl) {
    int i = blockIdx.x * blockDim.x + threadIdx.x;     // 0 .. NL*NE-1
    if (i >= NL * NE) return;
    int l = i >> 14;
    int j = i & (NE - 1);
    float e0 = emb[(size_t)l * 2 * NE + j];
    float e1 = emb[(size_t)l * 2 * NE + NE + j];
    uint32_t u0 = __float_as_uint(e0); u0 = (u0 + 0x7fffu + ((u0 >> 16) & 1u)) >> 16;  // RTNE bf16
    uint32_t u1 = __float_as_uint(e1); u1 = (u1 + 0x7fffu + ((u1 >> 16) & 1u)) >> 16;
    tbl[i] = u0 | (u1 << 16);
}

// -------- main: 4 pts/thread, single 64-KB LDS buffer, 2 blocks/CU, reg-staging --------
__global__ __launch_bounds__(BLK, 4)   // 4 waves/EU -> VGPR cap 128; 2 blocks/CU (64 KB LDS each)
void hashenc_kernel(const float* __restrict__ x, const uint32_t* __restrict__ tbl,
                    float* __restrict__ out) {
    __shared__ __align__(16) uint32_t lds[NE];         // 64 KB single buffer

    const int tid = threadIdx.x;
    const size_t pbase = (size_t)blockIdx.x * (BLK * PPT);

    // load this thread's 4 points (coalesced float3 reads)
    float pc[PPT][3];
    #pragma unroll
    for (int j = 0; j < PPT; ++j) {
        const float3 p = ((const float3*)x)[pbase + (size_t)j * BLK + tid];
        pc[j][0] = p.x; pc[j][1] = p.y; pc[j][2] = p.z;
    }

    // prologue: stage level 0 (512 threads x 8 x 16 B = 64 KB)
    {
        const uint4* g = (const uint4*)tbl;
        uint4 r[8];
        #pragma unroll
        for (int p = 0; p < 8; ++p) r[p] = g[p * BLK + tid];
        #pragma unroll
        for (int p = 0; p < 8; ++p) ((uint4*)lds)[p * BLK + tid] = r[p];
    }

    uint32_t accp[PPT][8];                             // pending half-group results (bf16x2)

    #pragma unroll
    for (int l = 0; l < NL; ++l) {
        __syncthreads();                               // staged table for level l visible

        // issue next level's staging loads NOW (latency hides under this level's gathers)
        uint4 r[8];
        if (l + 1 < NL) {
            const uint4* g = (const uint4*)(tbl + ((size_t)(l + 1) << 14));
            #pragma unroll
            for (int p = 0; p < 8; ++p) r[p] = g[p * BLK + tid];
        }

        const int   res  = kRes[l];
        const float fres = (float)res;
        const bool hashed = (res * res * res > NE);

        #pragma unroll
        for (int j = 0; j < PPT; ++j) {
            // grid_sample align_corners=False unnormalization
            float fr[3]; int c0[3];
            #pragma unroll
            for (int d = 0; d < 3; ++d) {
                float ix = ((pc[j][d] + 1.0f) * fres - 1.0f) * 0.5f;
                float fl = floorf(ix);
                fr[d] = ix - fl;
                c0[d] = (int)fl;                       // in [-1, res-1]
            }

            // per-dim validity-folded weights + index contributions
            float    w[3][2];
            uint32_t a[3][2];
            #pragma unroll
            for (int d = 0; d < 3; ++d) {
                const int lo = c0[d], hi = c0[d] + 1;
                w[d][0] = (lo >= 0)     ? (1.0f - fr[d]) : 0.0f;   // zero-padding
                w[d][1] = (hi <= res-1) ? fr[d]          : 0.0f;
                const int loc = lo < 0 ? 0 : lo;
                const int hic = hi > res - 1 ? res - 1 : hi;
                if (hashed) {
                    constexpr uint32_t P[3] = {1u, 2654435761u, 805459861u};
                    a[d][0] = (uint32_t)loc * P[d];
                    a[d][1] = (uint32_t)hic * P[d];
                } else {
                    const uint32_t stride = (d == 0) ? 1u : ((d == 1) ? (uint32_t)res
                                                                      : (uint32_t)(res * res));
                    a[d][0] = (uint32_t)loc * stride;
                    a[d][1] = (uint32_t)hic * stride;
                }
            }

            // pairwise-factored xy terms
            float    wxy[4];
            uint32_t axy[4];
            #pragma unroll
            for (int c = 0; c < 4; ++c) {
                const int bx = c & 1, by = (c >> 1) & 1;
                wxy[c] = w[0][bx] * w[1][by];
                axy[c] = hashed ? (a[0][bx] ^ a[1][by]) : (a[0][bx] + a[1][by]);
            }

            float f0 = 0.0f, f1 = 0.0f;
            #pragma unroll
            for (int c = 0; c < 8; ++c) {
                const int cxy = c & 3, bz = (c >> 2) & 1;
                const uint32_t idx = hashed
                    ? ((axy[cxy] ^ a[2][bz]) & (uint32_t)(NE - 1))
                    : (axy[cxy] + a[2][bz]);
                const float wt = wxy[cxy] * w[2][bz];
                const uint32_t v = lds[idx];
                f0 = fmaf(wt, __uint_as_float(v << 16),          f0);  // dim 0 (low bf16)
                f1 = fmaf(wt, __uint_as_float(v & 0xffff0000u),  f1);  // dim 1 (high bf16)
            }

            // pack to bf16x2 (round-to-nearest-up, <=0.5 ulp)
            const uint32_t u0 = (__float_as_uint(f0) + 0x8000u) >> 16;
            const uint32_t u1 = (__float_as_uint(f1) + 0x8000u) & 0xffff0000u;
            accp[j][l & 7] = u0 | u1;
        }

        if (l + 1 < NL) {
            __syncthreads();                           // all gathers of level l done
            #pragma unroll
            for (int p = 0; p < 8; ++p) ((uint4*)lds)[p * BLK + tid] = r[p];
        }

        // flush one 64-B half-line per point per 8-level group
        if ((l & 7) == 7) {
            const int half = l >> 3;
            #pragma unroll
            for (int j = 0; j < PPT; ++j) {
                const size_t pt = pbase + (size_t)j * BLK + tid;
                float4* o = (float4*)(out + pt * 32 + half * 16);
                #pragma unroll
                for (int q = 0; q < 4; ++q) {
                    const uint32_t v0 = accp[j][2 * q], v1 = accp[j][2 * q + 1];
                    o[q] = make_float4(__uint_as_float(v0 << 16),
                                       __uint_as_float(v0 & 0xffff0000u),
                                       __uint_as_float(v1 << 16),
                                       __uint_as_float(v1 & 0xffff0000u));
                }
            }
        }
    }
}

extern "C" void kernel_launch(void* const* d_in, const int* in_sizes, int n_in,
                              void* d_out, int out_size, void* d_ws, size_t ws_size,
                              hipStream_t stream) {
    const float* x   = (const float*)d_in[0];   // (B,3) fp32
    const float* emb = (const float*)d_in[1];   // (16,2,16384) fp32
    uint32_t* tbl = (uint32_t*)d_ws;            // (16,16384) packed bf16x2 = 1 MB
    float* out = (float*)d_out;                 // (B,16,2) fp32

    const int npack = NL * NE;
    pack_kernel<<<dim3((npack + 255) / 256), dim3(256), 0, stream>>>(emb, tbl);

    const int nblocks = (1 << 21) / (BLK * PPT);   // 1024 blocks of 2048 points
    hashenc_kernel<<<dim3(nblocks), dim3(BLK), 0, stream>>>(x, tbl, out);
}

// Round 5
// 1130.074 us; speedup vs baseline: 1.4198x; 1.4198x over previous
//
#include <hip/hip_runtime.h>
#include <stdint.h>

#define NL  16
#define NE  16384           // entries per level (power of two)
#define BLK 512             // threads per block
#define PPT 4               // points per thread -> 2048 points per block

constexpr int kRes[NL] = {16,20,25,32,40,50,64,80,101,128,161,203,256,322,406,512};

// ---------------- pre-pass: pack emb (L,2,NE) fp32 -> (L,NE) u32 of 2x bf16 ----------------
__global__ void pack_kernel(const float* __restrict__ emb, uint32_t* __restrict__ tbl) {
    int i = blockIdx.x * blockDim.x + threadIdx.x;     // 0 .. NL*NE-1
    if (i >= NL * NE) return;
    int l = i >> 14;
    int j = i & (NE - 1);
    float e0 = emb[(size_t)l * 2 * NE + j];
    float e1 = emb[(size_t)l * 2 * NE + NE + j];
    uint32_t u0 = __float_as_uint(e0); u0 = (u0 + 0x7fffu + ((u0 >> 16) & 1u)) >> 16;  // RTNE bf16
    uint32_t u1 = __float_as_uint(e1); u1 = (u1 + 0x7fffu + ((u1 >> 16) & 1u)) >> 16;
    tbl[i] = u0 | (u1 << 16);
}

// -------- main: 4 pts/thread, single 64-KB LDS buffer, 2 blocks/CU, reg-staging --------
// __launch_bounds__ 2nd arg: this toolchain's allocator budgets ~256/w VGPRs (R1/R2/R4
// evidence: w=4 -> 64, w=8 -> 32). w=2 -> 128-VGPR budget; 128 VGPR still allows
// 16 waves/CU = 2 blocks x 512, matching the 64-KB-LDS limit. Working set ~105 regs.
__global__ __launch_bounds__(BLK, 2)
void hashenc_kernel(const float* __restrict__ x, const uint32_t* __restrict__ tbl,
                    float* __restrict__ out) {
    __shared__ __align__(16) uint32_t lds[NE];         // 64 KB single buffer

    const int tid = threadIdx.x;
    const size_t pbase = (size_t)blockIdx.x * (BLK * PPT);

    // load this thread's 4 points (coalesced float3 reads)
    float pc[PPT][3];
    #pragma unroll
    for (int j = 0; j < PPT; ++j) {
        const float3 p = ((const float3*)x)[pbase + (size_t)j * BLK + tid];
        pc[j][0] = p.x; pc[j][1] = p.y; pc[j][2] = p.z;
    }

    // prologue: stage level 0 (512 threads x 8 x 16 B = 64 KB)
    {
        const uint4* g = (const uint4*)tbl;
        uint4 r[8];
        #pragma unroll
        for (int p = 0; p < 8; ++p) r[p] = g[p * BLK + tid];
        #pragma unroll
        for (int p = 0; p < 8; ++p) ((uint4*)lds)[p * BLK + tid] = r[p];
    }

    uint32_t accp[PPT][8];                             // pending half-group results (bf16x2)

    #pragma unroll
    for (int l = 0; l < NL; ++l) {
        __syncthreads();                               // staged table for level l visible

        // issue next level's staging loads NOW (latency hides under this level's gathers)
        uint4 r[8];
        if (l + 1 < NL) {
            const uint4* g = (const uint4*)(tbl + ((size_t)(l + 1) << 14));
            #pragma unroll
            for (int p = 0; p < 8; ++p) r[p] = g[p * BLK + tid];
        }

        const int   res  = kRes[l];
        const float hres = 0.5f * (float)res;          // unnorm: ix = p*hres + (hres-0.5)
        const float cadd = hres - 0.5f;
        const bool hashed = (res * res * res > NE);

        #pragma unroll
        for (int j = 0; j < PPT; ++j) {
            // grid_sample align_corners=False unnormalization (single fma per dim)
            float fr[3]; int c0[3];
            #pragma unroll
            for (int d = 0; d < 3; ++d) {
                float ix = fmaf(pc[j][d], hres, cadd);
                float fl = floorf(ix);
                fr[d] = ix - fl;
                c0[d] = (int)fl;                       // in [-1, res-1]
            }

            // per-dim validity-folded weights + index contributions
            float    w[3][2];
            uint32_t a[3][2];
            #pragma unroll
            for (int d = 0; d < 3; ++d) {
                const int lo = c0[d], hi = c0[d] + 1;
                w[d][0] = (lo >= 0)     ? (1.0f - fr[d]) : 0.0f;   // zero-padding
                w[d][1] = (hi <= res-1) ? fr[d]          : 0.0f;
                const int loc = lo < 0 ? 0 : lo;
                const int hic = hi > res - 1 ? res - 1 : hi;
                if (hashed) {
                    constexpr uint32_t P[3] = {1u, 2654435761u, 805459861u};
                    a[d][0] = (uint32_t)loc * P[d];
                    a[d][1] = (uint32_t)hic * P[d];
                } else {
                    const uint32_t stride = (d == 0) ? 1u : ((d == 1) ? (uint32_t)res
                                                                      : (uint32_t)(res * res));
                    a[d][0] = (uint32_t)loc * stride;
                    a[d][1] = (uint32_t)hic * stride;
                }
            }

            // pairwise-factored xy terms
            float    wxy[4];
            uint32_t axy[4];
            #pragma unroll
            for (int c = 0; c < 4; ++c) {
                const int bx = c & 1, by = (c >> 1) & 1;
                wxy[c] = w[0][bx] * w[1][by];
                axy[c] = hashed ? (a[0][bx] ^ a[1][by]) : (a[0][bx] + a[1][by]);
            }

            float f0 = 0.0f, f1 = 0.0f;
            #pragma unroll
            for (int c = 0; c < 8; ++c) {
                const int cxy = c & 3, bz = (c >> 2) & 1;
                const uint32_t idx = hashed
                    ? ((axy[cxy] ^ a[2][bz]) & (uint32_t)(NE - 1))
                    : (axy[cxy] + a[2][bz]);
                const float wt = wxy[cxy] * w[2][bz];
                const uint32_t v = lds[idx];
                f0 = fmaf(wt, __uint_as_float(v << 16),          f0);  // dim 0 (low bf16)
                f1 = fmaf(wt, __uint_as_float(v & 0xffff0000u),  f1);  // dim 1 (high bf16)
            }

            // pack to bf16x2 (round-to-nearest-up, <=0.5 ulp)
            const uint32_t u0 = (__float_as_uint(f0) + 0x8000u) >> 16;
            const uint32_t u1 = (__float_as_uint(f1) + 0x8000u) & 0xffff0000u;
            accp[j][l & 7] = u0 | u1;
        }

        if (l + 1 < NL) {
            __syncthreads();                           // all gathers of level l done
            #pragma unroll
            for (int p = 0; p < 8; ++p) ((uint4*)lds)[p * BLK + tid] = r[p];
        }

        // flush one 64-B half-line per point per 8-level group
        if ((l & 7) == 7) {
            const int half = l >> 3;
            #pragma unroll
            for (int j = 0; j < PPT; ++j) {
                const size_t pt = pbase + (size_t)j * BLK + tid;
                float4* o = (float4*)(out + pt * 32 + half * 16);
                #pragma unroll
                for (int q = 0; q < 4; ++q) {
                    const uint32_t v0 = accp[j][2 * q], v1 = accp[j][2 * q + 1];
                    o[q] = make_float4(__uint_as_float(v0 << 16),
                                       __uint_as_float(v0 & 0xffff0000u),
                                       __uint_as_float(v1 << 16),
                                       __uint_as_float(v1 & 0xffff0000u));
                }
            }
        }
    }
}

extern "C" void kernel_launch(void* const* d_in, const int* in_sizes, int n_in,
                              void* d_out, int out_size, void* d_ws, size_t ws_size,
                              hipStream_t stream) {
    const float* x   = (const float*)d_in[0];   // (B,3) fp32
    const float* emb = (const float*)d_in[1];   // (16,2,16384) fp32
    uint32_t* tbl = (uint32_t*)d_ws;            // (16,16384) packed bf16x2 = 1 MB
    float* out = (float*)d_out;                 // (B,16,2) fp32

    const int npack = NL * NE;
    pack_kernel<<<dim3((npack + 255) / 256), dim3(256), 0, stream>>>(emb, tbl);

    const int nblocks = (1 << 21) / (BLK * PPT);   // 1024 blocks of 2048 points
    hashenc_kernel<<<dim3(nblocks), dim3(BLK), 0, stream>>>(x, tbl, out);
}

// Round 6
// 229.630 us; speedup vs baseline: 6.9870x; 4.9213x over previous
//
#include <hip/hip_runtime.h>
#include <stdint.h>

#define NL  16
#define NE  16384           // entries per level (power of two)
#define BLK 1024            // threads per block == points per block

constexpr int kRes[NL] = {16,20,25,32,40,50,64,80,101,128,161,203,256,322,406,512};

// ---------------- pre-pass: pack emb (L,2,NE) fp32 -> (L,NE) u32 of 2x bf16 ----------------
__global__ void pack_kernel(const float* __restrict__ emb, uint32_t* __restrict__ tbl) {
    int i = blockIdx.x * blockDim.x + threadIdx.x;     // 0 .. NL*NE-1
    if (i >= NL * NE) return;
    int l = i >> 14;
    int j = i & (NE - 1);
    float e0 = emb[(size_t)l * 2 * NE + j];
    float e1 = emb[(size_t)l * 2 * NE + NE + j];
    uint32_t u0 = __float_as_uint(e0); u0 = (u0 + 0x7fffu + ((u0 >> 16) & 1u)) >> 16;  // RTNE bf16
    uint32_t u1 = __float_as_uint(e1); u1 = (u1 + 0x7fffu + ((u1 >> 16) & 1u)) >> 16;
    tbl[i] = u0 | (u1 << 16);
}

// ---- main: 1 pt/thread (R1's proven 64-VGPR codegen), single 64-KB buffer, 2 blocks/CU ----
__global__ __launch_bounds__(BLK, 4)   // cap 64 VGPR (R1 compiled to exactly 64, no spill)
void hashenc_kernel(const float* __restrict__ x, const uint32_t* __restrict__ tbl,
                    float* __restrict__ out) {
    __shared__ __align__(16) uint32_t lds[NE];         // 64 KB single buffer -> 2 blocks/CU

    const int tid  = threadIdx.x;
    const size_t b = (size_t)blockIdx.x * BLK + tid;

    const float3 p3 = ((const float3*)x)[b];
    const float pc[3] = {p3.x, p3.y, p3.z};

    // prologue: stage level 0 (1024 threads x 4 x 16 B = 64 KB), reg round-trip
    {
        const uint4* g = (const uint4*)tbl;
        uint4 r0 = g[0 * BLK + tid], r1 = g[1 * BLK + tid];
        uint4 r2 = g[2 * BLK + tid], r3 = g[3 * BLK + tid];
        uint4* dst = (uint4*)lds;
        dst[0 * BLK + tid] = r0; dst[1 * BLK + tid] = r1;
        dst[2 * BLK + tid] = r2; dst[3 * BLK + tid] = r3;
    }

    float acc[16];
    #pragma unroll
    for (int i = 0; i < 16; ++i) acc[i] = 0.0f;

    #pragma unroll
    for (int l = 0; l < NL; ++l) {
        __syncthreads();   // barrier A: staged table for level l visible

        // issue next level's staging loads NOW; latency hides under this level's gathers
        uint4 r0, r1, r2, r3;
        if (l + 1 < NL) {
            const uint4* g = (const uint4*)(tbl + ((size_t)(l + 1) << 14));
            r0 = g[0 * BLK + tid];
            r1 = g[1 * BLK + tid];
            r2 = g[2 * BLK + tid];
            r3 = g[3 * BLK + tid];
        }

        const int   res  = kRes[l];
        const float hres = 0.5f * (float)res;          // unnorm: ix = p*hres + (hres-0.5)
        const float cadd = hres - 0.5f;
        const bool hashed = (res * res * res > NE);

        // grid_sample align_corners=False unnormalization (1 fma per dim)
        float fr[3]; int c0[3];
        #pragma unroll
        for (int d = 0; d < 3; ++d) {
            float ix = fmaf(pc[d], hres, cadd);
            float fl = floorf(ix);
            fr[d] = ix - fl;
            c0[d] = (int)fl;                           // in [-1, res-1]
        }

        // per-dim validity-folded weights + index contributions
        float    w[3][2];
        uint32_t a[3][2];
        #pragma unroll
        for (int d = 0; d < 3; ++d) {
            const int lo = c0[d], hi = c0[d] + 1;
            w[d][0] = (lo >= 0)     ? (1.0f - fr[d]) : 0.0f;   // zero-padding
            w[d][1] = (hi <= res-1) ? fr[d]          : 0.0f;
            const int loc = lo < 0 ? 0 : lo;
            const int hic = hi > res - 1 ? res - 1 : hi;
            if (hashed) {
                constexpr uint32_t P[3] = {1u, 2654435761u, 805459861u};
                a[d][0] = (uint32_t)loc * P[d];
                a[d][1] = (uint32_t)hic * P[d];
            } else {
                const uint32_t stride = (d == 0) ? 1u : ((d == 1) ? (uint32_t)res
                                                                  : (uint32_t)(res * res));
                a[d][0] = (uint32_t)loc * stride;
                a[d][1] = (uint32_t)hic * stride;
            }
        }

        // pairwise-factored xy terms (12 ops instead of 16)
        float    wxy[4];
        uint32_t axy[4];
        #pragma unroll
        for (int c = 0; c < 4; ++c) {
            const int bx = c & 1, by = (c >> 1) & 1;
            wxy[c] = w[0][bx] * w[1][by];
            axy[c] = hashed ? (a[0][bx] ^ a[1][by]) : (a[0][bx] + a[1][by]);
        }

        float f0 = 0.0f, f1 = 0.0f;
        #pragma unroll
        for (int c = 0; c < 8; ++c) {
            const int cxy = c & 3, bz = (c >> 2) & 1;
            const uint32_t idx = hashed
                ? ((axy[cxy] ^ a[2][bz]) & (uint32_t)(NE - 1))
                : (axy[cxy] + a[2][bz]);
            const float wt = wxy[cxy] * w[2][bz];
            const uint32_t v = lds[idx];
            f0 = fmaf(wt, __uint_as_float(v << 16),          f0);  // dim 0 (low bf16)
            f1 = fmaf(wt, __uint_as_float(v & 0xffff0000u),  f1);  // dim 1 (high bf16)
        }
        acc[2 * (l & 7) + 0] = f0;
        acc[2 * (l & 7) + 1] = f1;

        // barrier B: all gathers of level l done -> safe to overwrite buffer
        if (l + 1 < NL) {
            __syncthreads();
            uint4* dst = (uint4*)lds;
            dst[0 * BLK + tid] = r0;
            dst[1 * BLK + tid] = r1;
            dst[2 * BLK + tid] = r2;
            dst[3 * BLK + tid] = r3;
        }

        // flush one 64-B half-line per point per 8-level group (R1's proven layout)
        if ((l & 7) == 7) {
            float4* o = (float4*)(out + b * 32 + (size_t)(l >> 3) * 16);
            o[0] = make_float4(acc[0],  acc[1],  acc[2],  acc[3]);
            o[1] = make_float4(acc[4],  acc[5],  acc[6],  acc[7]);
            o[2] = make_float4(acc[8],  acc[9],  acc[10], acc[11]);
            o[3] = make_float4(acc[12], acc[13], acc[14], acc[15]);
        }
    }
}

extern "C" void kernel_launch(void* const* d_in, const int* in_sizes, int n_in,
                              void* d_out, int out_size, void* d_ws, size_t ws_size,
                              hipStream_t stream) {
    const float* x   = (const float*)d_in[0];   // (B,3) fp32
    const float* emb = (const float*)d_in[1];   // (16,2,16384) fp32
    uint32_t* tbl = (uint32_t*)d_ws;            // (16,16384) packed bf16x2 = 1 MB
    float* out = (float*)d_out;                 // (B,16,2) fp32

    const int npack = NL * NE;
    pack_kernel<<<dim3((npack + 255) / 256), dim3(256), 0, stream>>>(emb, tbl);

    const int nblocks = (1 << 21) / BLK;        // B = 2^21 exactly divisible
    hashenc_kernel<<<dim3(nblocks), dim3(BLK), 0, stream>>>(x, tbl, out);
}